// Round 2
// baseline (156.129 us; speedup 1.0000x reference)
//
#include <hip/hip_runtime.h>
#include <hip/hip_bf16.h>

#define N_NODES 50000
#define N_EDGES 800000
#define D_IN 96
#define D_OUT 128
#define CAP 64              // deg ~ Poisson(16); P(deg>=64) ~ e^-41 -> no drops

// XCD-sliced fill: 8 slices x 6250 nodes; block group g = blockIdx&7 lands on
// XCD g (round-robin heuristic) and bins only dst in slice g -> bucket/cursor
// lines written from ONE XCD, merging in its L2 instead of churning HBM.
#define SLICES 8
#define NODES_PER_SLICE 6250
#define GROUP_BLOCKS 256
#define FILL_BLOCKS (SLICES * GROUP_BLOCKS)         // 2048
#define EDGES_PER_BLOCK 3125                        // 3125*256 = 800000 exactly
#define FILL_SLOTS 13                               // ceil(3125/256)

#define CONV_THREADS (N_NODES * 12)                 // 600000
#define CONV_BLOCKS ((CONV_THREADS + 255) / 256)    // 2344
#define WCONV_BLOCKS 12                             // 128*24 = 3072 = 12*256 tasks

// fused agg+gemm: 64 nodes per block (4 waves x 16-node MFMA tiles)
// XCD-aligned: slice g's nodes handled by blocks with blockIdx&7 == g so that
// cursor/bucket reads hit the L2 that the fill wrote.
#define NPB 64
#define SLICE_AG_BLOCKS ((NODES_PER_SLICE + NPB - 1) / NPB)   // 98
#define AG_BLOCKS (SLICES * SLICE_AG_BLOCKS)                  // 784
#define AH_PITCH 104        // u16/row (96 + 8 pad); 208 B = 13*16 B (b128-aligned)

typedef unsigned short u16;
typedef __attribute__((ext_vector_type(8))) short short8;   // 8 x bf16 (4 VGPRs)
typedef __attribute__((ext_vector_type(4))) float f32x4;

__device__ __forceinline__ u16 f2bf(float f) {
    unsigned u = __float_as_uint(f);
    unsigned r = (u + 0x7FFFu + ((u >> 16) & 1u)) >> 16;   // RNE
    return (u16)r;
}
__device__ __forceinline__ float bf2f(u16 h) {
    return __uint_as_float(((unsigned)h) << 16);
}

// ---------------------------------------------------------------------------
// K1: heterogeneous grid.
//   [0, FILL_BLOCKS): XCD-sliced edge binning, ILP-batched:
//     pass 1: 13 strided dst/src loads into registers (coalesced, independent)
//     pass 2: 13 exec-masked atomicAdds fired back-to-back (no waits between)
//     pass 3: drain + guarded bucket stores
//     (previous form was a dynamic loop with a dependent load->atomic->store
//      chain per iteration: VALUBusy 4.8%, HBM 20% -> pure latency bound)
//   [FILL_BLOCKS, +CONV_BLOCKS): xh = bf16(x) row-major.
//   [.., +WCONV_BLOCKS): Wfrag = bf16 B-fragment-layout [Wl|Wr] in global ws.
// ---------------------------------------------------------------------------
__global__ __launch_bounds__(256) void sage_fill_conv(
    const int* __restrict__ src,
    const int* __restrict__ dst,
    const float* __restrict__ x,
    const float* __restrict__ Wl,
    const float* __restrict__ Wr,
    int* __restrict__ cursor,
    u16* __restrict__ bucket,
    u16* __restrict__ xh,
    u16* __restrict__ Wfrag)
{
    const int b = blockIdx.x;
    if (b < FILL_BLOCKS) {
        const int slice = b & 7;
        const int gb = b >> 3;
        const int lo = slice * NODES_PER_SLICE;
        const int hi = lo + NODES_PER_SLICE;
        const int tid = (int)threadIdx.x;
        const int e0 = gb * EDGES_PER_BLOCK + tid;

        // pass 1: batch-load all slots (clamped addr for the invalid tail slot)
        int d[FILL_SLOTS], s[FILL_SLOTS];
#pragma unroll
        for (int i = 0; i < FILL_SLOTS; i++) {
            int valid = (tid + i * 256) < EDGES_PER_BLOCK;
            int e = valid ? (e0 + i * 256) : e0;
            d[i] = dst[e];
            s[i] = src[e];
        }

        // pass 2: fire all atomics; results land in distinct registers, no use
        // until pass 3 -> compiler issues them back-to-back.
        int pos[FILL_SLOTS];
#pragma unroll
        for (int i = 0; i < FILL_SLOTS; i++) {
            bool act = ((tid + i * 256) < EDGES_PER_BLOCK)
                       && (d[i] >= lo) && (d[i] < hi);
            pos[i] = act ? atomicAdd(&cursor[d[i]], 1) : CAP;
        }

        // pass 3: drain + store
#pragma unroll
        for (int i = 0; i < FILL_SLOTS; i++) {
            if (pos[i] < CAP)
                bucket[(size_t)d[i] * CAP + pos[i]] = (u16)s[i];
        }
    } else if (b < FILL_BLOCKS + CONV_BLOCKS) {
        unsigned t = (unsigned)(b - FILL_BLOCKS) * 256u + threadIdx.x;
        if (t >= (unsigned)CONV_THREADS) return;
        unsigned n = t / 12u;
        unsigned c8 = t - n * 12u;
        const float* p = x + (size_t)n * D_IN + c8 * 8u;
        short8 v;
#pragma unroll
        for (int i = 0; i < 8; i++) v[i] = (short)f2bf(p[i]);
        *(short8*)(xh + (size_t)n * D_IN + c8 * 8u) = v;
    } else {
        // W -> bf16 fragments: 128 j x 24 chunks (12 Wl + 12 Wr)
        int idx = (b - FILL_BLOCKS - CONV_BLOCKS) * 256 + (int)threadIdx.x; // <3072
        int j = idx / 24;
        int c8 = idx - j * 24;
        int kc = c8 >> 2;
        int quad = c8 & 3;
        const float* wsrc = (c8 < 12) ? (Wl + (size_t)j * D_IN + c8 * 8)
                                      : (Wr + (size_t)j * D_IN + (c8 - 12) * 8);
        int jt = j >> 4;
        int col = j & 15;
        short8 v;
#pragma unroll
        for (int i = 0; i < 8; i++) v[i] = (short)f2bf(wsrc[i]);
        *(short8*)(Wfrag + (((jt * 6 + kc) * 64) + col + 16 * quad) * 8) = v;
    }
}

// ---------------------------------------------------------------------------
// K2 (fused, high-occupancy): aggregate 64 nodes into LDS Ah, then MFMA.
// LDS = Ah only (13.3 KB). Blocks are XCD-aligned with fill slices:
// g = blockIdx&7, nodes [g*6250 + k*64, ...) -> cursor/bucket reads are
// local-L2 hits (same XCD that binned them).
// Phase A: 768 tasks (node m, chunk c8), 3/thread; bucket indices loaded
//          8-at-a-time (b128), 8 row-gathers in flight.
// Phase B: per-wave 16-node tile; A-frags: Ah (kc 0..2) + xh global (3..5);
//          B-frags: coalesced b128 loads from Wfrag (L2-broadcast).
// Epilogue: C/D map col=lane&15, row=quad*4+r (m89/m91-verified).
// ---------------------------------------------------------------------------
__global__ __launch_bounds__(256) void sage_agg_gemm(
    const u16* __restrict__ xh,
    const int* __restrict__ cursor,
    const u16* __restrict__ bucket,
    const u16* __restrict__ Wfrag,
    const float* __restrict__ bl,
    float* __restrict__ out)
{
    __shared__ u16 Ah[NPB * AH_PITCH];      // 13312 B

    const int tid = threadIdx.x;
    const int g = blockIdx.x & 7;
    const int kblk = blockIdx.x >> 3;                 // [0, 98)
    const int n0 = g * NODES_PER_SLICE + kblk * NPB;
    const int hi_s = (g + 1) * NODES_PER_SLICE;       // slice end (<= N_NODES)

    // ---- phase A: aggregate the block's 64 nodes into Ah ----
#pragma unroll
    for (int rep = 0; rep < 3; rep++) {
        int task = rep * 256 + tid;          // 0..767
        int m = task / 12;
        int c8 = task - m * 12;
        int n = n0 + m;

        float acc[8];
#pragma unroll
        for (int i = 0; i < 8; i++) acc[i] = 0.0f;
        float invd = 0.0f;

        if (n < hi_s) {
            int deg = cursor[n];
            int degc = deg < CAP ? deg : CAP;
            const u16* brow = bucket + (size_t)n * CAP;
            int e = 0;
            for (; e + 8 <= degc; e += 8) {
                short8 id = *(const short8*)(brow + e);   // 8 indices, one b128
                short8 v[8];
#pragma unroll
                for (int q = 0; q < 8; q++) {
                    unsigned s = (u16)id[q];
                    v[q] = *(const short8*)(xh + s * (unsigned)D_IN + c8 * 8u);
                }
#pragma unroll
                for (int q = 0; q < 8; q++)
#pragma unroll
                    for (int i = 0; i < 8; i++) acc[i] += bf2f((u16)v[q][i]);
            }
            if (e + 4 <= degc) {
                unsigned s0 = brow[e + 0];
                unsigned s1 = brow[e + 1];
                unsigned s2 = brow[e + 2];
                unsigned s3 = brow[e + 3];
                short8 v0 = *(const short8*)(xh + s0 * (unsigned)D_IN + c8 * 8u);
                short8 v1 = *(const short8*)(xh + s1 * (unsigned)D_IN + c8 * 8u);
                short8 v2 = *(const short8*)(xh + s2 * (unsigned)D_IN + c8 * 8u);
                short8 v3 = *(const short8*)(xh + s3 * (unsigned)D_IN + c8 * 8u);
#pragma unroll
                for (int i = 0; i < 8; i++)
                    acc[i] += bf2f((u16)v0[i]) + bf2f((u16)v1[i])
                            + bf2f((u16)v2[i]) + bf2f((u16)v3[i]);
                e += 4;
            }
            for (; e < degc; e++) {
                unsigned s = brow[e];
                short8 v = *(const short8*)(xh + s * (unsigned)D_IN + c8 * 8u);
#pragma unroll
                for (int i = 0; i < 8; i++) acc[i] += bf2f((u16)v[i]);
            }
            invd = 1.0f / fmaxf((float)deg, 1.0f);
        }

        short8 o;
#pragma unroll
        for (int i = 0; i < 8; i++) o[i] = (short)f2bf(acc[i] * invd);
        *(short8*)(Ah + m * AH_PITCH + c8 * 8) = o;
    }
    __syncthreads();

    // ---- phase B: 16-node MFMA tile per wave ----
    const int wave = tid >> 6;
    const int lane = tid & 63;
    const int m16 = lane & 15;
    const int quad = lane >> 4;
    const int tilebase = n0 + wave * 16;
    if (tilebase >= hi_s) return;            // single barrier already passed

    int nn = tilebase + m16;
    nn = nn < hi_s ? nn : hi_s - 1;          // clamp A-row source (store guarded)

    const u16* arow = Ah + (wave * 16 + m16) * AH_PITCH + quad * 8;
    const u16* xrow = xh + (size_t)nn * D_IN + quad * 8;
    short8 a[6];
#pragma unroll
    for (int kc = 0; kc < 3; kc++) a[kc]     = *(const short8*)(arow + kc * 32);
#pragma unroll
    for (int kc = 0; kc < 3; kc++) a[3 + kc] = *(const short8*)(xrow + kc * 32);

#pragma unroll
    for (int jt = 0; jt < 8; jt++) {
        f32x4 acc = {0.0f, 0.0f, 0.0f, 0.0f};
#pragma unroll
        for (int kc = 0; kc < 6; kc++) {
            short8 bfrag = *(const short8*)(Wfrag + ((jt * 6 + kc) * 64 + lane) * 8);
            acc = __builtin_amdgcn_mfma_f32_16x16x32_bf16(a[kc], bfrag, acc, 0, 0, 0);
        }
        const int j = jt * 16 + m16;         // col = lane&15
        const float bj = bl[j];
#pragma unroll
        for (int r = 0; r < 4; r++) {
            int row = quad * 4 + r;
            int n = tilebase + row;
            if (n < hi_s)
                out[(size_t)n * D_OUT + j] = fmaxf(acc[r] + bj, 0.0f);
        }
    }
}

extern "C" void kernel_launch(void* const* d_in, const int* in_sizes, int n_in,
                              void* d_out, int out_size, void* d_ws, size_t ws_size,
                              hipStream_t stream) {
    const float* x   = (const float*)d_in[0];
    const int* eidx  = (const int*)d_in[1];
    const float* Wl  = (const float*)d_in[2];
    const float* bl  = (const float*)d_in[3];
    const float* Wr  = (const float*)d_in[4];
    float* out = (float*)d_out;

    const int* src = eidx;                // edge_index[0]
    const int* dst = eidx + N_EDGES;      // edge_index[1]

    // ws: cursor 200192 B | bucket u16 6.4 MB | xh bf16 9.6 MB | Wfrag 49 KB
    char* ws = (char*)d_ws;
    int* cursor = (int*)ws;
    u16* bucket = (u16*)(ws + 200192);
    u16* xh     = (u16*)(ws + 200192 + 6400000);
    u16* Wfrag  = (u16*)(ws + 200192 + 6400000 + 9600000);

    hipMemsetAsync(cursor, 0, N_NODES * sizeof(int), stream);

    {
        dim3 grid(FILL_BLOCKS + CONV_BLOCKS + WCONV_BLOCKS);   // 4404
        sage_fill_conv<<<grid, 256, 0, stream>>>(src, dst, x, Wl, Wr,
                                                 cursor, bucket, xh, Wfrag);
    }
    {
        dim3 grid(AG_BLOCKS);                                  // 784
        sage_agg_gemm<<<grid, 256, 0, stream>>>(xh, cursor, bucket, Wfrag, bl, out);
    }
}